// Round 14
// baseline (755.317 us; speedup 1.0000x reference)
//
#include <hip/hip_runtime.h>
#include <math.h>

// VisualAttention — bf16x3 MFMA with PRE-SPLIT hi/lo planes + global_load_lds.
//   t = text@W + b; attn = softmax(obj@t^T); out = attn@t
// obj[8,1024,512] text[32768,768] W[768,512] b[512] -> out[8,1024,512] (fp32)
//
// Round 14 = round 13 resubmit (broker timeout; kernel unmeasured).
// m97-template port. All GEMM operands stored as bf16 hi/lo planes
// (split ONCE by producers; numerically identical to in-loop split4 of r3-r12).
// GEMM: 128x128 tile, BK=32, 256 thr = 4 waves (2x2), wave tile 64x64,
// global_load_lds staging (linear LDS dest, inverse-swizzled per-lane global
// source, swizzled frag read: granule (r,q) holds k-chunk (q-(r>>1))&3).
// ws = 370MB: text_hl 96 | obj_hl 16 | t_hl 64 | tT_hl 64 | WT_hl 2 | attn_f32 128
//      (attn_hl 128 aliased over text/obj/t_h after K2 — those are dead by then)

typedef unsigned short u16;
typedef u16 u16x4 __attribute__((ext_vector_type(4)));
typedef u16 u16x8 __attribute__((ext_vector_type(8)));
typedef __bf16 bf16x8 __attribute__((ext_vector_type(8)));
typedef float f32x4 __attribute__((ext_vector_type(4)));

__device__ inline void split4(const float4 v, u16x4* h4, u16x4* l4) {
  const float xs[4] = {v.x, v.y, v.z, v.w};
#pragma unroll
  for (int c = 0; c < 4; c++) {
    __bf16 hb = (__bf16)xs[c];
    __bf16 lb = (__bf16)(xs[c] - (float)hb);
    (*h4)[c] = __builtin_bit_cast(u16, hb);
    (*l4)[c] = __builtin_bit_cast(u16, lb);
  }
}

// async global->LDS, 16B per lane; LDS dest = uniform base + lane*16 (HW)
__device__ inline void gload_lds16(const u16* g, u16* l) {
  __builtin_amdgcn_global_load_lds(
      (const __attribute__((address_space(1))) unsigned int*)g,
      (__attribute__((address_space(3))) unsigned int*)l, 16, 0, 0);
}

// ---------------- pre-split bf16x3 NT GEMM ----------------
// C[M,N] = A[M,K] * B[N,K]^T via (Ah+Al)(Bh+Bl) ~= AlBh + AhBl + AhBh.
// MODE 0: C fp32 (K2/K4).  MODE 1: K1 epilogue (bias; writes t h/l AND tT h/l).
template<int MODE>
__global__ __launch_bounds__(256, 2) void gemm_x3(
    const u16* __restrict__ Ah, const u16* __restrict__ Al,
    const u16* __restrict__ Bh, const u16* __restrict__ Bl,
    float* __restrict__ C, const float* __restrict__ bias,
    u16* __restrict__ th, u16* __restrict__ tl,
    u16* __restrict__ tTh, u16* __restrict__ tTl,
    int M, int N, int K, long sA, long sB, long sC)
{
  // planes: 0=A_h 1=A_l 2=B_h 3=B_l; each [2 dbuf][128 rows][4 granules x 8 u16]
  __shared__ __align__(16) u16 sh[4][2][4096];   // 64 KB total

  const int m0 = blockIdx.y * 128;
  const int n0 = blockIdx.x * 128;
  const int t    = threadIdx.x;
  const int lane = t & 63;
  const int w    = t >> 6;        // wave 0..3
  const int wm   = w >> 1;        // 2x2 wave grid, 64x64 out per wave
  const int wn   = w & 1;
  const int lr   = lane & 15;     // frag row/col  [m89/m91 layout]
  const int lg   = lane >> 4;     // k-group: k = lg*8 + j

  const u16* Abh = Ah + (long)blockIdx.z * sA;
  const u16* Abl = Al + (long)blockIdx.z * sA;
  const u16* Bbh = Bh + (long)blockIdx.z * sB;
  const u16* Bbl = Bl + (long)blockIdx.z * sB;
  float*     Cb  = C  + (long)blockIdx.z * sC;

  // wave w stages plane w: per-lane global src, linear LDS dest
  const u16* wsrc; long wrow;
  if      (w == 0) { wsrc = Abh; wrow = (long)m0 * K; }
  else if (w == 1) { wsrc = Abl; wrow = (long)m0 * K; }
  else if (w == 2) { wsrc = Bbh; wrow = (long)n0 * K; }
  else             { wsrc = Bbl; wrow = (long)n0 * K; }

  // frag read offsets (u16 units within one plane buffer), loop-invariant.
  // read of (row ar, kgroup lg) uses swizzled granule q' = (lg + (ar>>1)) & 3
  int offA[4], offB[4];
#pragma unroll
  for (int i = 0; i < 4; i++) {
    const int ar = wm * 64 + i * 16 + lr;
    offA[i] = ar * 32 + (((lg + (ar >> 1)) & 3) << 3);
    const int br = wn * 64 + i * 16 + lr;
    offB[i] = br * 32 + (((lg + (br >> 1)) & 3) << 3);
  }

  f32x4 acc[4][4];
#pragma unroll
  for (int i = 0; i < 4; i++)
#pragma unroll
    for (int j = 0; j < 4; j++) acc[i][j] = (f32x4){0.f, 0.f, 0.f, 0.f};

  // stage one 128x32 k-tile of this wave's plane into buffer NB.
  // lane l of instr ii writes LDS granule G = ii*64+l -> (r,q)=(G>>2,G&3);
  // inverse swizzle: that granule must hold global k-chunk kq = (q-(r>>1))&3.
  #define STAGE(NB, K0)                                                        \
    {                                                                          \
      u16* lb = &sh[w][NB][0];                                                 \
      _Pragma("unroll")                                                        \
      for (int ii = 0; ii < 8; ii++) {                                         \
        const int G  = ii * 64 + lane;                                         \
        const int rr = G >> 2, qq = G & 3;                                     \
        const int kq = (qq - (rr >> 1)) & 3;                                   \
        gload_lds16(wsrc + wrow + (long)rr * K + (K0) + kq * 8, lb + ii * 512);\
      }                                                                        \
    }

  STAGE(0, 0)
  __syncthreads();               // compiler drains vmcnt before barrier: tile0 ready

  const int nk = K >> 5;
  int cur = 0;
  for (int kt = 0; kt < nk; ++kt) {
    if (kt + 1 < nk) STAGE(cur ^ 1, (kt + 1) << 5)   // async, lands by next barrier

    const u16* P0 = &sh[0][cur][0];
    const u16* P1 = &sh[1][cur][0];
    const u16* P2 = &sh[2][cur][0];
    const u16* P3 = &sh[3][cur][0];
    bf16x8 ah[4], al[4], bh[4], bl[4];
#pragma unroll
    for (int i = 0; i < 4; i++) {
      ah[i] = __builtin_bit_cast(bf16x8, *(const u16x8*)(P0 + offA[i]));
      al[i] = __builtin_bit_cast(bf16x8, *(const u16x8*)(P1 + offA[i]));
      bh[i] = __builtin_bit_cast(bf16x8, *(const u16x8*)(P2 + offB[i]));
      bl[i] = __builtin_bit_cast(bf16x8, *(const u16x8*)(P3 + offB[i]));
    }
    // term order per acc: lh, hl, hh (identical to r3-r12 summation order)
#pragma unroll
    for (int i = 0; i < 4; i++)
#pragma unroll
      for (int j = 0; j < 4; j++)
        acc[i][j] = __builtin_amdgcn_mfma_f32_16x16x32_bf16(al[i], bh[j], acc[i][j], 0, 0, 0);
#pragma unroll
    for (int i = 0; i < 4; i++)
#pragma unroll
      for (int j = 0; j < 4; j++)
        acc[i][j] = __builtin_amdgcn_mfma_f32_16x16x32_bf16(ah[i], bl[j], acc[i][j], 0, 0, 0);
#pragma unroll
    for (int i = 0; i < 4; i++)
#pragma unroll
      for (int j = 0; j < 4; j++)
        acc[i][j] = __builtin_amdgcn_mfma_f32_16x16x32_bf16(ah[i], bh[j], acc[i][j], 0, 0, 0);

    __syncthreads();             // drains stage writes + frag reads of cur
    cur ^= 1;
  }
  #undef STAGE

  // epilogue: C/D frag col=lane&15, row=4*(lane>>4)+reg  [m89-verified]
  if (MODE == 0) {
#pragma unroll
    for (int j = 0; j < 4; j++) {
      const int col = n0 + wn * 64 + j * 16 + lr;
#pragma unroll
      for (int i = 0; i < 4; i++) {
        const int row = m0 + wm * 64 + i * 16 + lg * 4;
#pragma unroll
        for (int r = 0; r < 4; r++)
          Cb[(long)(row + r) * N + col] = acc[i][j][r];
      }
    }
  } else {
    // K1: N=512, M=32768 (8 batches x 4096 rows). Write t h/l and tT h/l.
#pragma unroll
    for (int j = 0; j < 4; j++) {
      const int col = n0 + wn * 64 + j * 16 + lr;
      const float bj = bias[col];
#pragma unroll
      for (int i = 0; i < 4; i++) {
        const int row = m0 + wm * 64 + i * 16 + lg * 4;
        float4 vv;
        vv.x = acc[i][j][0] + bj; vv.y = acc[i][j][1] + bj;
        vv.z = acc[i][j][2] + bj; vv.w = acc[i][j][3] + bj;
        u16x4 h4, l4;
        split4(vv, &h4, &l4);
#pragma unroll
        for (int r = 0; r < 4; r++) {
          th[(long)(row + r) * 512 + col] = h4[r];
          tl[(long)(row + r) * 512 + col] = l4[r];
        }
        const int b = row >> 12, rl = row & 4095;   // rows r..r+3 same batch (tiles 128-aligned)
        const long ti = (long)b * (512L * 4096) + (long)col * 4096 + rl;
        *(u16x4*)(tTh + ti) = h4;
        *(u16x4*)(tTl + ti) = l4;
      }
    }
  }
}

// ---------------- fp32 -> bf16 hi/lo planes (elementwise) ----------------
__global__ __launch_bounds__(256) void split_pair(
    const float* __restrict__ in, u16* __restrict__ h, u16* __restrict__ l, long n4)
{
  for (long i = blockIdx.x * 256 + threadIdx.x; i < n4; i += (long)gridDim.x * 256) {
    float4 v = ((const float4*)in)[i];
    u16x4 h4, l4;
    split4(v, &h4, &l4);
    ((u16x4*)h)[i] = h4;
    ((u16x4*)l)[i] = l4;
  }
}

// ---------------- W[768,512] -> WT[512,768] bf16 hi/lo (transpose+split) ----------------
__global__ __launch_bounds__(256) void prep_W(
    const float* __restrict__ W, u16* __restrict__ WTh, u16* __restrict__ WTl)
{
  __shared__ float tile[32][33];
  const int c  = blockIdx.x * 32 + threadIdx.x;   // W col
  const int r0 = blockIdx.y * 32 + threadIdx.y;   // W row
#pragma unroll
  for (int j = 0; j < 32; j += 8)
    tile[threadIdx.y + j][threadIdx.x] = W[(r0 + j) * 512 + c];
  __syncthreads();
  const int c2 = blockIdx.y * 32 + threadIdx.x;   // WT col = W row
  const int r2 = blockIdx.x * 32 + threadIdx.y;   // WT row = W col
#pragma unroll
  for (int j = 0; j < 32; j += 8) {
    const float v = tile[threadIdx.x][threadIdx.y + j];
    const __bf16 hb = (__bf16)v;
    const __bf16 lb = (__bf16)(v - (float)hb);
    WTh[(r2 + j) * 768 + c2] = __builtin_bit_cast(u16, hb);
    WTl[(r2 + j) * 768 + c2] = __builtin_bit_cast(u16, lb);
  }
}

// ---------------- softmax over rows of 4096: fp32 in, bf16 hi/lo out ----------------
__device__ inline float wave_max(float x) {
#pragma unroll
  for (int o = 1; o < 64; o <<= 1) x = fmaxf(x, __shfl_xor(x, o, 64));
  return x;
}
__device__ inline float wave_sum(float x) {
#pragma unroll
  for (int o = 1; o < 64; o <<= 1) x += __shfl_xor(x, o, 64);
  return x;
}

__global__ __launch_bounds__(256) void softmax4096_hl(
    const float* __restrict__ attn, u16* __restrict__ ah, u16* __restrict__ al)
{
  __shared__ float red[4];
  const float* p = attn + (long)blockIdx.x * 4096;
  u16* ph = ah + (long)blockIdx.x * 4096;
  u16* pl = al + (long)blockIdx.x * 4096;
  const int t = threadIdx.x;

  float4 v[4];
  float mx = -3.4e38f;
#pragma unroll
  for (int i = 0; i < 4; i++) {
    v[i] = *reinterpret_cast<const float4*>(p + i * 1024 + t * 4);
    mx = fmaxf(mx, fmaxf(fmaxf(v[i].x, v[i].y), fmaxf(v[i].z, v[i].w)));
  }
  mx = wave_max(mx);
  if ((t & 63) == 0) red[t >> 6] = mx;
  __syncthreads();
  mx = fmaxf(fmaxf(red[0], red[1]), fmaxf(red[2], red[3]));
  __syncthreads();

  float s = 0.f;
#pragma unroll
  for (int i = 0; i < 4; i++) {
    v[i].x = __expf(v[i].x - mx); s += v[i].x;
    v[i].y = __expf(v[i].y - mx); s += v[i].y;
    v[i].z = __expf(v[i].z - mx); s += v[i].z;
    v[i].w = __expf(v[i].w - mx); s += v[i].w;
  }
  s = wave_sum(s);
  if ((t & 63) == 0) red[t >> 6] = s;
  __syncthreads();
  const float r = 1.f / (red[0] + red[1] + red[2] + red[3]);

#pragma unroll
  for (int i = 0; i < 4; i++) {
    v[i].x *= r; v[i].y *= r; v[i].z *= r; v[i].w *= r;
    u16x4 h4, l4;
    split4(v[i], &h4, &l4);
    *(u16x4*)(ph + i * 1024 + t * 4) = h4;
    *(u16x4*)(pl + i * 1024 + t * 4) = l4;
  }
}

extern "C" void kernel_launch(void* const* d_in, const int* in_sizes, int n_in,
                              void* d_out, int out_size, void* d_ws, size_t ws_size,
                              hipStream_t stream)
{
  const float* obj  = (const float*)d_in[0];  // [8,1024,512]
  const float* text = (const float*)d_in[1];  // [32768,768]
  const float* W    = (const float*)d_in[2];  // [768,512]
  const float* bias = (const float*)d_in[3];  // [512]
  float*       out  = (float*)d_out;          // [8,1024,512]

  char* base = (char*)d_ws;
  const long MB = 1024L * 1024;
  u16* text_h = (u16*)(base + 0 * MB);     // 48MB
  u16* text_l = (u16*)(base + 48 * MB);    // 48MB
  u16* obj_h  = (u16*)(base + 96 * MB);    // 8MB
  u16* obj_l  = (u16*)(base + 104 * MB);   // 8MB
  u16* t_h    = (u16*)(base + 112 * MB);   // 32MB
  u16* t_l    = (u16*)(base + 144 * MB);   // 32MB
  u16* tT_h   = (u16*)(base + 176 * MB);   // 32MB
  u16* tT_l   = (u16*)(base + 208 * MB);   // 32MB
  u16* WT_h   = (u16*)(base + 240 * MB);   // 0.75MB
  u16* WT_l   = (u16*)(base + 241 * MB);   // 0.75MB
  float* attn_f32 = (float*)(base + 242 * MB);  // 128MB -> total 370MB
  // aliased over [0,128MB) AFTER K2 (text/obj/t_h all dead by then):
  u16* attn_h = (u16*)(base + 0 * MB);     // 64MB
  u16* attn_l = (u16*)(base + 64 * MB);    // 64MB

  // P0: WT hi/lo
  prep_W<<<dim3(16, 24), dim3(32, 8), 0, stream>>>(W, WT_h, WT_l);
  // P1/P2: split text and obj
  split_pair<<<2048, 256, 0, stream>>>(text, text_h, text_l, 32768L * 768 / 4);
  split_pair<<<2048, 256, 0, stream>>>(obj, obj_h, obj_l, 8192L * 512 / 4);
  // K1: t = text @ WT^T + bias  (M=32768 N=512 K=768) -> t h/l + tT h/l
  gemm_x3<1><<<dim3(4, 256, 1), 256, 0, stream>>>(
      text_h, text_l, WT_h, WT_l, nullptr, bias, t_h, t_l, tT_h, tT_l,
      32768, 512, 768, 0L, 0L, 0L);
  // K2: attn = obj @ t^T (per batch)  M=1024 N=4096 K=512 -> fp32
  gemm_x3<0><<<dim3(32, 8, 8), 256, 0, stream>>>(
      obj_h, obj_l, t_h, t_l, attn_f32, nullptr, nullptr, nullptr, nullptr, nullptr,
      1024, 4096, 512, 1024L * 512, 4096L * 512, 1024L * 4096);
  // K3: softmax rows -> attn h/l (aliased over dead region)
  softmax4096_hl<<<8192, 256, 0, stream>>>(attn_f32, attn_h, attn_l);
  // K4: out = attn @ tT^T (per batch)  M=1024 N=512 K=4096
  gemm_x3<0><<<dim3(4, 8, 8), 256, 0, stream>>>(
      attn_h, attn_l, tT_h, tT_l, out, nullptr, nullptr, nullptr, nullptr, nullptr,
      1024, 512, 4096, 1024L * 4096, 512L * 4096, 1024L * 512);
}